// Round 11
// baseline (10869.637 us; speedup 1.0000x reference)
//
#include <hip/hip_runtime.h>
#include <math.h>

#define B_   32
#define INS  1000
#define TS   999           // recurrent steps (t = 0..998)
#define D_   128
#define U_   512
#define G3   1536
#define OUTS 100
#define NB   212           // 16 LX + 64 L0 + 64 L1 + 64 L2 + 4 aggregators
#define NTHR 512

// ws layout (floats)
#define HBUF_OFF 0                       // [4][3][512][32]  (step&3, layer, k, e)
#define HBUF_SZ  (4*3*512*32)            // 196608
#define RING_OFF HBUF_SZ                 // [4][1536][32]    mx0 ring (step&3)
#define RING_SZ  (4*1536*32)             // 196608
#define BAR_OFF  (RING_OFF + RING_SZ)    // 4096 u32
// slots: [j*64+b]*16 (layers j=0..2), [192+b]*16 (LX). value = steps completed.
// flags: FLAG(j) = bar[(216+j)*16], j=0..2 layers, 3=LX. Published by aggregators.

// LDS layout (floats): same as r9/r10
#define W_CHK1  3080
#define W_CHK0  1544
#define XBUF_OFF 12288
#define PART_OFF 24640
#define SMEM_FLOATS 32384
#define PIDX3(q,g,c,e) ((q)*968 + ((g)*8+(c))*40 + (e))

#define WT_STORE(p, v) __hip_atomic_store((p), (v), __ATOMIC_RELAXED, __HIP_MEMORY_SCOPE_AGENT)
#define CG_LOAD(p)     __hip_atomic_load((p), __ATOMIC_RELAXED, __HIP_MEMORY_SCOPE_AGENT)
#define FLAGP(bar, j)  (&(bar)[(216 + (j)) * 16])

#define FMA12() \
  acc[0][0]=fmaf(av.x,w0,acc[0][0]); acc[0][1]=fmaf(av.y,w0,acc[0][1]); \
  acc[0][2]=fmaf(av.z,w0,acc[0][2]); acc[0][3]=fmaf(av.w,w0,acc[0][3]); \
  acc[1][0]=fmaf(av.x,w1,acc[1][0]); acc[1][1]=fmaf(av.y,w1,acc[1][1]); \
  acc[1][2]=fmaf(av.z,w1,acc[1][2]); acc[1][3]=fmaf(av.w,w1,acc[1][3]); \
  acc[2][0]=fmaf(av.x,w2,acc[2][0]); acc[2][1]=fmaf(av.y,w2,acc[2][1]); \
  acc[2][2]=fmaf(av.z,w2,acc[2][2]); acc[2][3]=fmaf(av.w,w2,acc[2][3]);

#define LD16(DST, PTR) { _Pragma("unroll") \
  for (int t_ = 0; t_ < 16; ++t_) DST[t_] = *(const float4*)((PTR) + t_*32); }

#define FMA16(BUF) { _Pragma("unroll") \
  for (int t_ = 0; t_ < 16; ++t_) { \
    const float w0 = wp[0], w1 = wp[1], w2 = wp[2]; \
    const float4 av = BUF[t_]; \
    FMA12(); \
    wp += 24; } }

__global__ void gru_init_kernel(const float* __restrict__ s0,
                                const float* __restrict__ s1,
                                const float* __restrict__ s2,
                                float* __restrict__ ws) {
  int g = blockIdx.x * 256 + threadIdx.x;
  if (g < 4096) { unsigned* bar = (unsigned*)(ws + BAR_OFF); bar[g] = 0u; }
  // h_j(-1) lives at ring parity (-1)&3 = 3, for all layers
  for (int i = g; i < 3 * 512 * 32; i += gridDim.x * 256) {
    int which = i / (512 * 32);
    int r = i - which * (512 * 32);
    int k = r >> 5, e = r & 31;
    const float* s = (which == 0) ? s0 : ((which == 1) ? s1 : s2);
    ws[HBUF_OFF + 3 * 49152 + which * 16384 + k * 32 + e] = s[k];
  }
}

// Decongested dependency wait: 1-3 threads poll per-layer FLAGS (published by
// aggregator blocks), not 64 per-block slots. Targets identical to r10:
//   own flag >= t, upstream flag >= t+1, downstream flag >= t-3.
__device__ __forceinline__ void wait_flags(unsigned* bar, int role, int t) {
  const int tid = threadIdx.x;
  const unsigned* p = nullptr; int tgt = 0;
  if (role < 0) {
    if (tid == 0)      { p = FLAGP(bar, 0); tgt = t - 3; }
  } else if (role == 0) {
    if (tid == 0)      { p = FLAGP(bar, 0); tgt = t;     }
    else if (tid == 1) { p = FLAGP(bar, 3); tgt = t + 1; }
    else if (tid == 2) { p = FLAGP(bar, 1); tgt = t - 3; }
  } else if (role == 1) {
    if (tid == 0)      { p = FLAGP(bar, 1); tgt = t;     }
    else if (tid == 1) { p = FLAGP(bar, 0); tgt = t + 1; }
    else if (tid == 2) { p = FLAGP(bar, 2); tgt = t - 3; }
  } else {
    if (tid == 0)      { p = FLAGP(bar, 2); tgt = t;     }
    else if (tid == 1) { p = FLAGP(bar, 1); tgt = t + 1; }
  }
  if (p && tgt > 0) {
    while ((int)CG_LOAD(p) < tgt) __builtin_amdgcn_s_sleep(2);
  }
  __syncthreads();
  if (role >= 0) {    // LX reads nothing cross-block -> no fence needed
    if (tid == 0) __builtin_amdgcn_fence(__ATOMIC_ACQUIRE, "agent");
    __syncthreads();
  }
}

// Publish step completion: entry __syncthreads drains vmcnt -> all WT data
// stores are at the coherence point before the slot store issues.
__device__ __forceinline__ void publish(unsigned* slots, int sidx, int t) {
  __syncthreads();
  if (threadIdx.x == 0) WT_STORE(&slots[sidx * 16], (unsigned)(t + 1));
}

__global__ __launch_bounds__(NTHR, 1) void gru_persist(
    const float* __restrict__ x,
    const float* __restrict__ W0c, const float* __restrict__ U0c, const float* __restrict__ b0c,
    const float* __restrict__ W1c, const float* __restrict__ U1c, const float* __restrict__ b1c,
    const float* __restrict__ W2c, const float* __restrict__ U2c, const float* __restrict__ b2c,
    const float* __restrict__ Wd, const float* __restrict__ bd,
    float* __restrict__ out, float* __restrict__ ws)
{
  float* hbuf = ws + HBUF_OFF;
  float* ring = ws + RING_OFF;
  unsigned* slots = (unsigned*)(ws + BAR_OFF);
  float* pred_out = out;                       // [32][100][128]
  float* hid_out  = out + B_ * OUTS * D_;      // [32][100][3][512]

  const int bid = blockIdx.x;
  const int tid = threadIdx.x;

  // ---- aggregator blocks: poll 64 (16) slots in parallel, publish ONE flag ----
  if (bid >= 208) {
    const int aj   = bid - 208;                 // 0,1,2 = layers; 3 = LX
    const int base = (aj < 3) ? aj * 64 : 192;
    const int n    = (aj < 3) ? 64 : 16;
    for (int T = 1; T <= TS; ++T) {
      if (tid < n) {
        while ((int)CG_LOAD(&slots[(base + tid) * 16]) < T) __builtin_amdgcn_s_sleep(2);
      }
      __syncthreads();
      if (tid == 0) WT_STORE(FLAGP(slots, aj), (unsigned)T);
    }
    // fall through to readout below
  } else {

  int role, rb;
  if      (bid < 16)  { role = -1; rb = bid; }
  else if (bid < 80)  { role = 0;  rb = bid - 16; }
  else if (bid < 144) { role = 1;  rb = bid - 80; }
  else                { role = 2;  rb = bid - 144; }
  const int sidx = (role < 0) ? (192 + rb) : (role * 64 + rb);

  __shared__ float smem[SMEM_FLOATS];     // 126.5 KiB
  float* part = smem + PART_OFF;

  const int eg  = tid & 7;
  const int c_l = (tid >> 3) & 7;
  const int q   = tid >> 6;
  const int cb  = (rb & 7) * 8 + (rb >> 3);
  const int c0  = cb * 8;
  const int rc = tid >> 5;
  const int re = tid & 31;
  const int xb0 = ((rb & 7) * 2 + (rb >> 3)) * 96;
  const int cg3 = (tid & 31) * 3;
  const int e0  = (tid >> 5) * 2;

  const float *Wj = nullptr, *Ujp = nullptr, *bj = nullptr;
  if      (role == 0) { Ujp = U0c; bj = b0c; }
  else if (role == 1) { Wj = W1c; Ujp = U1c; bj = b1c; }
  else if (role == 2) { Wj = W2c; Ujp = U2c; bj = b2c; }

  // ---- one-time staging ----
  if (role < 0) {
    for (int idx = tid; idx < 128 * 96; idx += NTHR)
      smem[idx] = W0c[(idx / 96) * G3 + xb0 + (idx % 96)];
    for (int f = tid; f < 1024; f += NTHR) {
      int e = f >> 5, d4 = (f & 31) * 4;
      *(float4*)(smem + XBUF_OFF + e * 128 + d4) =
          *(const float4*)(x + e * (INS * D_) + d4);
    }
  } else {
    const int chunk = (role == 0) ? 64 : 128;
    const int chks  = (role == 0) ? W_CHK0 : W_CHK1;
    const int total = 8 * chunk * 24;
    for (int idx = tid; idx < total; idx += NTHR) {
      int qq = idx / (chunk * 24);
      int r  = idx - qq * (chunk * 24);
      int i  = r / 24;
      int cg = r - i * 24;
      int c  = cg / 3, g = cg - c * 3;
      const float* mat; int row;
      if (role == 0)      { mat = Ujp; row = qq * 64 + i; }
      else if (qq < 4)    { mat = Wj;  row = qq * 128 + i; }
      else                { mat = Ujp; row = (qq - 4) * 128 + i; }
      smem[qq * chks + (i * 8 + c) * 3 + g] = mat[row * G3 + g * 512 + c0 + c];
    }
  }
  float bz = 0.f, br = 0.f, b0h = 0.f, b1h = 0.f;
  if (role >= 0 && tid < 256) {
    const int cg2 = c0 + rc;
    bz  = bj[cg2] + bj[G3 + cg2];
    br  = bj[512 + cg2] + bj[G3 + 512 + cg2];
    b0h = bj[1024 + cg2];
    b1h = bj[G3 + 1024 + cg2];
  }
  __syncthreads();

  // ---- self-timed step loop ----
  for (int t = 0; t < TS; ++t) {
    wait_flags(slots, role, t);

    if (role < 0) {
      float4 xp0, xp1;
      const bool pf = (t + 1) < TS;
      if (pf) {
        int f0 = tid, f1 = tid + 512;
        xp0 = *(const float4*)(x + (f0 >> 5) * (INS * D_) + (t + 1) * D_ + (f0 & 31) * 4);
        xp1 = *(const float4*)(x + (f1 >> 5) * (INS * D_) + (t + 1) * D_ + (f1 & 31) * 4);
      }
      const float* xb = smem + XBUF_OFF + (t & 1) * 4096;
      float acc[3][2];
      #pragma unroll
      for (int c = 0; c < 3; ++c) { acc[c][0] = 0.f; acc[c][1] = 0.f; }
      #pragma unroll 4
      for (int k4 = 0; k4 < D_; k4 += 4) {
        float4 v0 = *(const float4*)(xb + e0 * 128 + k4);
        float4 v1 = *(const float4*)(xb + (e0 + 1) * 128 + k4);
        float xs0[4] = {v0.x, v0.y, v0.z, v0.w};
        float xs1[4] = {v1.x, v1.y, v1.z, v1.w};
        #pragma unroll
        for (int kk = 0; kk < 4; ++kk) {
          const float* wpx = smem + (k4 + kk) * 96 + cg3;
          float w0 = wpx[0], w1 = wpx[1], w2 = wpx[2];
          acc[0][0] = fmaf(xs0[kk], w0, acc[0][0]);
          acc[0][1] = fmaf(xs1[kk], w0, acc[0][1]);
          acc[1][0] = fmaf(xs0[kk], w1, acc[1][0]);
          acc[1][1] = fmaf(xs1[kk], w1, acc[1][1]);
          acc[2][0] = fmaf(xs0[kk], w2, acc[2][0]);
          acc[2][1] = fmaf(xs1[kk], w2, acc[2][1]);
        }
      }
      float* dst = ring + (t & 3) * (G3 * 32);
      #pragma unroll
      for (int c = 0; c < 3; ++c) {
        WT_STORE(dst + (xb0 + cg3 + c) * 32 + e0,     acc[c][0]);
        WT_STORE(dst + (xb0 + cg3 + c) * 32 + e0 + 1, acc[c][1]);
      }
      if (pf) {
        float* xw = smem + XBUF_OFF + ((t + 1) & 1) * 4096;
        int f0 = tid, f1 = tid + 512;
        *(float4*)(xw + (f0 >> 5) * 128 + (f0 & 31) * 4) = xp0;
        *(float4*)(xw + (f1 >> 5) * 128 + (f1 & 31) * 4) = xp1;
      }
    } else {
      const int j = role;
      const float* hown = hbuf + ((t + 3) & 3) * 49152;   // h(t-1) parity
      const float* hup  = hbuf + (t & 3) * 49152;         // h_{j-1}(t) parity
      float xz = 0.f, xr2 = 0.f, xhv0 = 0.f, hp = 0.f;
      if (tid < 256) {
        const int cg2 = c0 + rc;
        hp = hown[j * 16384 + cg2 * 32 + re];
        if (j == 0) {
          const float* r3 = ring + (t & 3) * (G3 * 32);
          xz   = r3[cg2 * 32 + re];
          xr2  = r3[(512 + cg2) * 32 + re];
          xhv0 = r3[(1024 + cg2) * 32 + re];
        }
      }

      float acc[3][4];
      #pragma unroll
      for (int g2 = 0; g2 < 3; ++g2)
        #pragma unroll
        for (int i2 = 0; i2 < 4; ++i2) acc[g2][i2] = 0.f;

      float4 bufA[16], bufB[16], bufC[16];
      if (j == 0) {
        const float* Ab = hown + (q * 64) * 32 + eg * 4;
        const float* wp = smem + q * W_CHK0 + c_l * 3;
        LD16(bufA, Ab);        LD16(bufB, Ab + 512);
        LD16(bufC, Ab + 1024); FMA16(bufA);
        LD16(bufA, Ab + 1536); FMA16(bufB);
        FMA16(bufC);
        FMA16(bufA);
      } else {
        const int kb = (q & 3) * 128;
        const float* Ab = ((q < 4) ? (hup + (j - 1) * 16384) : (hown + j * 16384))
                          + kb * 32 + eg * 4;
        const float* wp = smem + q * W_CHK1 + c_l * 3;
        LD16(bufA, Ab);        LD16(bufB, Ab + 512);
        LD16(bufC, Ab + 1024); FMA16(bufA);
        LD16(bufA, Ab + 1536); FMA16(bufB);
        LD16(bufB, Ab + 2048); FMA16(bufC);
        LD16(bufC, Ab + 2560); FMA16(bufA);
        LD16(bufA, Ab + 3072); FMA16(bufB);
        LD16(bufB, Ab + 3584); FMA16(bufC);
        FMA16(bufA);
        FMA16(bufB);
      }
      #pragma unroll
      for (int g2 = 0; g2 < 3; ++g2) {
        *(float4*)&part[PIDX3(q, g2, c_l, eg * 4)] =
            make_float4(acc[g2][0], acc[g2][1], acc[g2][2], acc[g2][3]);
      }
      __syncthreads();

      if (tid < 256) {
        float gz = 0.f, gr = 0.f, xh = 0.f, hh = 0.f;
        #pragma unroll
        for (int q2 = 0; q2 < 8; ++q2) {
          gz += part[PIDX3(q2, 0, rc, re)];
          gr += part[PIDX3(q2, 1, rc, re)];
          float v = part[PIDX3(q2, 2, rc, re)];
          if (j == 0)       hh += v;
          else if (q2 < 4)  xh += v;
          else              hh += v;
        }
        const int cg2 = c0 + rc;
        const float xhv = (j == 0) ? xhv0 : xh;
        const float zi = gz + xz + bz;
        const float ri = gr + xr2 + br;
        const float z = 1.f / (1.f + expf(-zi));
        const float r = 1.f / (1.f + expf(-ri));
        const float cand = tanhf((xhv + b0h) + r * (hh + b1h));
        const float hn = z * hp + (1.f - z) * cand;
        WT_STORE(&hbuf[(t & 3) * 49152 + j * 16384 + cg2 * 32 + re], hn);
        if (t >= TS - OUTS) {
          WT_STORE(&hid_out[((re * OUTS + (t - (TS - OUTS))) * 3 + j) * U_ + cg2], hn);
        }
      }
    }
    publish(slots, sidx, t);
  }
  }  // end compute-block branch

  // ---- readout: wait for layer-2 flag, one acquire, then pred ----
  {
    unsigned* slots2 = (unsigned*)(ws + BAR_OFF);
    if (tid == 0) {
      while ((int)CG_LOAD(FLAGP(slots2, 2)) < TS) __builtin_amdgcn_s_sleep(2);
    }
    __syncthreads();
    if (tid == 0) __builtin_amdgcn_fence(__ATOMIC_ACQUIRE, "agent");
    __syncthreads();
  }

  const int gt = bid * NTHR + tid;
  for (int o = gt; o < B_ * OUTS * D_; o += NB * NTHR) {
    int b  = o / (OUTS * D_);
    int r2 = o - b * (OUTS * D_);
    int s  = r2 >> 7;
    int dd = r2 & 127;
    const float* ys = hid_out + ((b * OUTS + s) * 3 + 2) * U_;
    float acc = bd[dd];
    #pragma unroll 4
    for (int k = 0; k < U_; k += 4) {
      float4 yv = *(const float4*)(ys + k);
      acc = fmaf(yv.x, Wd[(k    ) * D_ + dd], acc);
      acc = fmaf(yv.y, Wd[(k + 1) * D_ + dd], acc);
      acc = fmaf(yv.z, Wd[(k + 2) * D_ + dd], acc);
      acc = fmaf(yv.w, Wd[(k + 3) * D_ + dd], acc);
    }
    pred_out[o] = acc;
  }
}

extern "C" void kernel_launch(void* const* d_in, const int* in_sizes, int n_in,
                              void* d_out, int out_size, void* d_ws, size_t ws_size,
                              hipStream_t stream) {
  const float* x  = (const float*)d_in[0];
  const float* W0 = (const float*)d_in[1];
  const float* U0 = (const float*)d_in[2];
  const float* b0 = (const float*)d_in[3];
  const float* s0 = (const float*)d_in[4];
  const float* W1 = (const float*)d_in[5];
  const float* U1 = (const float*)d_in[6];
  const float* b1 = (const float*)d_in[7];
  const float* s1 = (const float*)d_in[8];
  const float* W2 = (const float*)d_in[9];
  const float* U2 = (const float*)d_in[10];
  const float* b2 = (const float*)d_in[11];
  const float* s2 = (const float*)d_in[12];
  const float* Wd = (const float*)d_in[13];
  const float* bd = (const float*)d_in[14];
  float* ws = (float*)d_ws;

  gru_init_kernel<<<192, 256, 0, stream>>>(s0, s1, s2, ws);
  gru_persist<<<NB, NTHR, 0, stream>>>(x, W0, U0, b0, W1, U1, b1,
                                       W2, U2, b2, Wd, bd, (float*)d_out, ws);
}